// Round 1
// baseline (350.990 us; speedup 1.0000x reference)
//
#include <hip/hip_runtime.h>

// ---------------------------------------------------------------------------
// Fused 5-layer GRU (SEQ=1, h0=0) + FC for MI355X (gfx950).
//
// Since T=1 and h0=0:  gh = b_hh  (w_hh is never used).
// Per layer:  a   = x @ w_ih^T             (MFMA 16x16x32 bf16, 6 N-tiles)
//             a_r += b_ih_r + b_hh_r  (folded into acc init)
//             a_z += b_ih_z + b_hh_z  (folded into acc init)
//             a_n += b_ih_n           (folded into acc init)
//             r = sigmoid(a_r); h = sigmoid(-a_z) * tanh(a_n + r*b_hh_n)
// Final: out = h5 @ fc_w^T + fc_b  (2 N-tiles), fp32 store.
//
// Precision: split-A — activations carried as bf16 hi+lo pairs, two MFMAs
// per tile (acc = mfma(Ahi,B, mfma(Alo,B,bias))). Removes activation-quant
// error; only weight bf16-quant error remains.
// ---------------------------------------------------------------------------

typedef __attribute__((ext_vector_type(8))) short bf16x8;
typedef __attribute__((ext_vector_type(4))) float f32x4;

#define NLAYER 5
#define HB_ST  40  // hbuf row stride in bf16 elements (80 B: 16B-aligned rows)

__device__ __forceinline__ float fexp2(float x) {
#if __has_builtin(__builtin_amdgcn_exp2f)
    return __builtin_amdgcn_exp2f(x);
#else
    return exp2f(x);
#endif
}
__device__ __forceinline__ float frcp(float x) {
#if __has_builtin(__builtin_amdgcn_rcpf)
    return __builtin_amdgcn_rcpf(x);
#else
    return 1.0f / x;
#endif
}

__device__ __forceinline__ unsigned short bf_rne(float f) {
    union { float f; unsigned u; } v; v.f = f;
    unsigned r = v.u + 0x7fffu + ((v.u >> 16) & 1u);
    return (unsigned short)(r >> 16);
}
__device__ __forceinline__ float bf_to_f(unsigned short h) {
    union { float f; unsigned u; } v; v.u = ((unsigned)h) << 16;
    return v.f;
}

__device__ __forceinline__ f32x4 mfma16(bf16x8 a, bf16x8 b, f32x4 c) {
    return __builtin_amdgcn_mfma_f32_16x16x32_bf16(a, b, c, 0, 0, 0);
}

// h = sigmoid(-az) * tanh(an + sigmoid(ar)*cn)
//   = [ez*(1-en)] / [(1+ez)*(1+en)],  ez=e^{-az}, en=e^{-2(an+r*cn)}
__device__ __forceinline__ float gru_act(float ar, float az, float an, float cn) {
    const float NL2E = -1.4426950408889634f;
    float er = fexp2(ar * NL2E);
    float r  = frcp(1.0f + er);
    float ez = fexp2(az * NL2E);
    float a2 = an + r * cn;
    float en = fexp2(a2 * (2.0f * NL2E));
    float num = ez * (1.0f - en);
    float den = (1.0f + ez) * (1.0f + en);
    return num * frcp(den);
}

struct Lds {
    unsigned short wB[NLAYER * 96 * 32];  // B-operand [l][n][k] == w_ih layout
    unsigned short wF[32 * 32];           // fc_w [n][k] (row-major as given)
    float brz[NLAYER * 64];               // b_ih+b_hh for r (0..31) and z (32..63)
    float bn_[NLAYER * 32];               // b_ih n-gate
    float cn_[NLAYER * 32];               // b_hh n-gate (multiplied by r)
    float fb_[32];                        // fc_b
    unsigned short hbuf[4 * 2 * 16 * HB_ST];  // [wave][plane hi/lo][row][col]
};

__global__ __launch_bounds__(256, 3) void gru_fused(
    const float* __restrict__ x, const float* __restrict__ w_ih,
    const float* __restrict__ b_ih, const float* __restrict__ b_hh,
    const float* __restrict__ fc_w, const float* __restrict__ fc_b,
    float* __restrict__ out, int nTiles)
{
    __shared__ Lds s;
    const int tid = threadIdx.x;

    // ---- stage weights / biases into LDS (once per block) ----
    for (int i = tid; i < NLAYER * 96 * 32; i += 256) s.wB[i] = bf_rne(w_ih[i]);
    for (int i = tid; i < 32 * 32; i += 256)          s.wF[i] = bf_rne(fc_w[i]);
    for (int i = tid; i < NLAYER * 64; i += 256) {
        int l = i >> 6, c = i & 63;
        s.brz[i] = b_ih[l * 96 + c] + b_hh[l * 96 + c];
    }
    for (int i = tid; i < NLAYER * 32; i += 256) {
        int l = i >> 5, c = i & 31;
        s.bn_[i] = b_ih[l * 96 + 64 + c];
        s.cn_[i] = b_hh[l * 96 + 64 + c];
    }
    if (tid < 32) s.fb_[tid] = fc_b[tid];
    __syncthreads();

    const int lane = tid & 63;
    const int n0 = lane & 15;     // A-row / B-col / C-col index
    const int q  = lane >> 4;     // k-group (A/B), row-group (C/D)
    unsigned short* hb  = s.hbuf + (tid >> 6) * (2 * 16 * HB_ST);
    unsigned short* hb2 = hb + 16 * HB_ST;

    const int waveId = (int)((blockIdx.x * blockDim.x + tid) >> 6);
    const int nWaves = (int)((gridDim.x * blockDim.x) >> 6);

    for (int tile = waveId; tile < nTiles; tile += nWaves) {
        const int rowBase = tile * 16;

        // ---- load x A-fragment: row = n0, k = q*8 .. q*8+7, split hi/lo ----
        const float4* xv = (const float4*)(x + (size_t)(rowBase + n0) * 32 + q * 8);
        float4 xa = xv[0], xb = xv[1];
        float xf[8] = {xa.x, xa.y, xa.z, xa.w, xb.x, xb.y, xb.z, xb.w};
        bf16x8 aHi, aLo;
        #pragma unroll
        for (int j = 0; j < 8; ++j) {
            unsigned short h = bf_rne(xf[j]);
            aHi[j] = (short)h;
            aLo[j] = (short)bf_rne(xf[j] - bf_to_f(h));
        }

        #pragma unroll
        for (int l = 0; l < NLAYER; ++l) {
            const unsigned short* wb = s.wB + l * 96 * 32;
            bf16x8 b0 = *(const bf16x8*)(wb + (0 * 16 + n0) * 32 + q * 8);
            bf16x8 b1 = *(const bf16x8*)(wb + (1 * 16 + n0) * 32 + q * 8);
            bf16x8 b2 = *(const bf16x8*)(wb + (2 * 16 + n0) * 32 + q * 8);
            bf16x8 b3 = *(const bf16x8*)(wb + (3 * 16 + n0) * 32 + q * 8);
            bf16x8 b4 = *(const bf16x8*)(wb + (4 * 16 + n0) * 32 + q * 8);
            bf16x8 b5 = *(const bf16x8*)(wb + (5 * 16 + n0) * 32 + q * 8);

            float brA = s.brz[l * 64 + n0],      brB = s.brz[l * 64 + 16 + n0];
            float bzA = s.brz[l * 64 + 32 + n0], bzB = s.brz[l * 64 + 48 + n0];
            float bnA = s.bn_[l * 32 + n0],      bnB = s.bn_[l * 32 + 16 + n0];
            float cnA = s.cn_[l * 32 + n0],      cnB = s.cn_[l * 32 + 16 + n0];

            f32x4 aR0 = {brA, brA, brA, brA}, aR1 = {brB, brB, brB, brB};
            f32x4 aZ0 = {bzA, bzA, bzA, bzA}, aZ1 = {bzB, bzB, bzB, bzB};
            f32x4 aN0 = {bnA, bnA, bnA, bnA}, aN1 = {bnB, bnB, bnB, bnB};

            aR0 = mfma16(aLo, b0, aR0); aR0 = mfma16(aHi, b0, aR0);
            aR1 = mfma16(aLo, b1, aR1); aR1 = mfma16(aHi, b1, aR1);
            aZ0 = mfma16(aLo, b2, aZ0); aZ0 = mfma16(aHi, b2, aZ0);
            aZ1 = mfma16(aLo, b3, aZ1); aZ1 = mfma16(aHi, b3, aZ1);
            aN0 = mfma16(aLo, b4, aN0); aN0 = mfma16(aHi, b4, aN0);
            aN1 = mfma16(aLo, b5, aN1); aN1 = mfma16(aHi, b5, aN1);

            // ---- activations: 4 rows x 2 col-halves per lane ----
            float hA[4], hB[4];
            #pragma unroll
            for (int i = 0; i < 4; ++i) {
                hA[i] = gru_act(aR0[i], aZ0[i], aN0[i], cnA);
                hB[i] = gru_act(aR1[i], aZ1[i], aN1[i], cnB);
            }

            // ---- C-layout -> A-layout via per-wave LDS round-trip ----
            #pragma unroll
            for (int i = 0; i < 4; ++i) {
                int row = q * 4 + i;
                unsigned short h1 = bf_rne(hA[i]);
                unsigned short h2 = bf_rne(hB[i]);
                hb [row * HB_ST + n0]      = h1;
                hb [row * HB_ST + 16 + n0] = h2;
                hb2[row * HB_ST + n0]      = bf_rne(hA[i] - bf_to_f(h1));
                hb2[row * HB_ST + 16 + n0] = bf_rne(hB[i] - bf_to_f(h2));
            }
            // wave-private buffer: drain writes, then read (same-wave LDS is
            // in-order in HW; the asm blocks stop compiler reordering).
            asm volatile("s_waitcnt lgkmcnt(0)" ::: "memory");
            aHi = *(const bf16x8*)(hb  + n0 * HB_ST + q * 8);
            aLo = *(const bf16x8*)(hb2 + n0 * HB_ST + q * 8);
            asm volatile("" ::: "memory");
        }

        // ---- FC: out = h5 @ fc_w^T + fc_b ----
        bf16x8 f0 = *(const bf16x8*)(s.wF + n0 * 32 + q * 8);
        bf16x8 f1 = *(const bf16x8*)(s.wF + (16 + n0) * 32 + q * 8);
        float fbA = s.fb_[n0], fbB = s.fb_[16 + n0];
        f32x4 o0 = {fbA, fbA, fbA, fbA};
        f32x4 o1 = {fbB, fbB, fbB, fbB};
        o0 = mfma16(aLo, f0, o0); o0 = mfma16(aHi, f0, o0);
        o1 = mfma16(aLo, f1, o1); o1 = mfma16(aHi, f1, o1);

        float* op = out + (size_t)rowBase * 32;
        #pragma unroll
        for (int i = 0; i < 4; ++i) {
            int row = q * 4 + i;
            op[row * 32 + n0]      = o0[i];
            op[row * 32 + 16 + n0] = o1[i];
        }
    }
}

extern "C" void kernel_launch(void* const* d_in, const int* in_sizes, int n_in,
                              void* d_out, int out_size, void* d_ws, size_t ws_size,
                              hipStream_t stream) {
    (void)n_in; (void)d_ws; (void)ws_size; (void)out_size;
    const float* x    = (const float*)d_in[0];
    const float* w_ih = (const float*)d_in[1];
    // d_in[2] = w_hh: unused (h0 == 0, T == 1)
    const float* b_ih = (const float*)d_in[3];
    const float* b_hh = (const float*)d_in[4];
    const float* fc_w = (const float*)d_in[5];
    const float* fc_b = (const float*)d_in[6];
    float* out = (float*)d_out;

    const int batch  = in_sizes[0] / 32;   // 1048576
    const int nTiles = batch / 16;         // 65536 (batch is a multiple of 16)

    // 768 blocks = 3 blocks/CU resident (LDS ~45.7 KB/block caps at 3).
    gru_fused<<<768, 256, 0, stream>>>(x, w_ih, b_ih, b_hh, fc_w, fc_b, out, nTiles);
}

// Round 2
// 328.086 us; speedup vs baseline: 1.0698x; 1.0698x over previous
//
#include <hip/hip_runtime.h>

// ---------------------------------------------------------------------------
// Fused 5-layer GRU (SEQ=1, h0=0) + FC for MI355X (gfx950).  Round 2.
//
// Orientation: C^T = W @ h^T  (A = weight tile [gate][k], B = h^T [k][batch]).
// MFMA C/D layout (16x16x32): col = lane&15 = BATCH, row = q*4+i = gate row.
// Next layer's B-operand frag also keys on batch = lane&15, so the
// C->B transform through per-wave LDS uses packed ds_write_b64 (conflict-free,
// stride-40 rows) and ds_read_b128. Biases enter as f32x4 acc-init loaded
// straight from LDS (bias varies along the row index == register index).
//
// Precision: split-B — activations carried as bf16 hi+lo planes, two MFMAs
// per tile. Only weight bf16-quant error remains (absmax ~4e-3 measured).
// ---------------------------------------------------------------------------

typedef __attribute__((ext_vector_type(8))) short bf16x8;
typedef __attribute__((ext_vector_type(4))) float f32x4;
typedef __attribute__((ext_vector_type(4))) unsigned short u16x4;

#define NLAYER 5
#define HB_ST  40  // hbuf row stride in bf16 elems (80 B rows: 16B-aligned, 2-way-free banks)

__device__ __forceinline__ float fexp2(float x) {
#if __has_builtin(__builtin_amdgcn_exp2f)
    return __builtin_amdgcn_exp2f(x);
#else
    return exp2f(x);
#endif
}
__device__ __forceinline__ float frcp(float x) {
#if __has_builtin(__builtin_amdgcn_rcpf)
    return __builtin_amdgcn_rcpf(x);
#else
    return 1.0f / x;
#endif
}

__device__ __forceinline__ unsigned short bf_rne(float f) {
    union { float f; unsigned u; } v; v.f = f;
    unsigned r = v.u + 0x7fffu + ((v.u >> 16) & 1u);
    return (unsigned short)(r >> 16);
}
__device__ __forceinline__ unsigned short bf_trunc(float f) {
    union { float f; unsigned u; } v; v.f = f;
    return (unsigned short)(v.u >> 16);
}
__device__ __forceinline__ float bf_to_f(unsigned short h) {
    union { float f; unsigned u; } v; v.u = ((unsigned)h) << 16;
    return v.f;
}

__device__ __forceinline__ f32x4 mfma16(bf16x8 a, bf16x8 b, f32x4 c) {
    return __builtin_amdgcn_mfma_f32_16x16x32_bf16(a, b, c, 0, 0, 0);
}

// h = sigmoid(-az) * tanh(an + sigmoid(ar)*cn)
//   = [ez*(1-en)] / [(1+ez)*(1+en)],  ez=e^{-az}, en=e^{-2(an+r*cn)}
__device__ __forceinline__ float gru_act(float ar, float az, float an, float cn) {
    const float NL2E = -1.4426950408889634f;
    float er = fexp2(ar * NL2E);
    float r  = frcp(1.0f + er);
    float ez = fexp2(az * NL2E);
    float a2 = an + r * cn;
    float en = fexp2(a2 * (2.0f * NL2E));
    float num = ez * (1.0f - en);
    float den = (1.0f + ez) * (1.0f + en);
    return num * frcp(den);
}

struct Lds {
    unsigned short wA[NLAYER * 96 * 32];  // A-operand [l][gate][k] == w_ih layout
    unsigned short wF[32 * 32];           // fc_w [emb][k] (row-major as given)
    float bsum[NLAYER * 96];              // r,z: b_ih+b_hh ; n: b_ih only
    float cn_[NLAYER * 32];               // b_hh n-gate (multiplied by r)
    float fb_[32];                        // fc_b
    unsigned short hbuf[8 * 2 * 16 * HB_ST];  // [wave][plane hi/lo][batch row][hid]
};

__global__ __launch_bounds__(512, 4) void gru_fused(
    const float* __restrict__ x, const float* __restrict__ w_ih,
    const float* __restrict__ b_ih, const float* __restrict__ b_hh,
    const float* __restrict__ fc_w, const float* __restrict__ fc_b,
    float* __restrict__ out, int nTiles)
{
    __shared__ Lds s;
    const int tid = threadIdx.x;
    const int NT = 512;

    // ---- stage weights / biases into LDS (once per block) ----
    for (int i = tid; i < NLAYER * 96 * 32; i += NT) s.wA[i] = bf_rne(w_ih[i]);
    for (int i = tid; i < 32 * 32; i += NT)          s.wF[i] = bf_rne(fc_w[i]);
    for (int i = tid; i < NLAYER * 96; i += NT) {
        int c = i % 96;
        s.bsum[i] = b_ih[i] + (c < 64 ? b_hh[i] : 0.0f);
    }
    for (int i = tid; i < NLAYER * 32; i += NT) {
        int l = i >> 5, c = i & 31;
        s.cn_[i] = b_hh[l * 96 + 64 + c];
    }
    if (tid < 32) s.fb_[tid] = fc_b[tid];
    __syncthreads();

    const int lane = tid & 63;
    const int n0 = lane & 15;     // batch-col (B n-index / C col)
    const int q  = lane >> 4;     // k-group (A/B), row-group (C/D)
    unsigned short* hb  = s.hbuf + (tid >> 6) * (2 * 16 * HB_ST);
    unsigned short* hb2 = hb + 16 * HB_ST;

    const int waveId = (int)((blockIdx.x * blockDim.x + tid) >> 6);
    const int nWaves = (int)((gridDim.x * blockDim.x) >> 6);

    for (int tile = waveId; tile < nTiles; tile += nWaves) {
        const int rowBase = tile * 16;

        // ---- load x as B-frag: batch = rowBase+n0, k = q*8..q*8+7, split hi/lo
        const float4* xv = (const float4*)(x + (size_t)(rowBase + n0) * 32 + q * 8);
        float4 xa = xv[0], xb = xv[1];
        float xf[8] = {xa.x, xa.y, xa.z, xa.w, xb.x, xb.y, xb.z, xb.w};
        bf16x8 bHi, bLo;
        #pragma unroll
        for (int j = 0; j < 8; ++j) {
            unsigned short h = bf_rne(xf[j]);
            bHi[j] = (short)h;
            bLo[j] = (short)bf_trunc(xf[j] - bf_to_f(h));
        }

        #pragma unroll
        for (int l = 0; l < NLAYER; ++l) {
            const unsigned short* wb = s.wA + l * 96 * 32;
            // A-frags: weight tile t rows t*16+n0... wait A row m = lane&15 = n0
            bf16x8 a0 = *(const bf16x8*)(wb + (0 * 16 + n0) * 32 + q * 8);
            bf16x8 a1 = *(const bf16x8*)(wb + (1 * 16 + n0) * 32 + q * 8);
            bf16x8 a2 = *(const bf16x8*)(wb + (2 * 16 + n0) * 32 + q * 8);
            bf16x8 a3 = *(const bf16x8*)(wb + (3 * 16 + n0) * 32 + q * 8);
            bf16x8 a4 = *(const bf16x8*)(wb + (4 * 16 + n0) * 32 + q * 8);
            bf16x8 a5 = *(const bf16x8*)(wb + (5 * 16 + n0) * 32 + q * 8);

            // acc init = bias f32x4 (rows q*4..q*4+3 of each 16-row gate tile)
            const float* bs = s.bsum + l * 96;
            f32x4 cR0 = *(const f32x4*)(bs + 0  + q * 4);
            f32x4 cR1 = *(const f32x4*)(bs + 16 + q * 4);
            f32x4 cZ0 = *(const f32x4*)(bs + 32 + q * 4);
            f32x4 cZ1 = *(const f32x4*)(bs + 48 + q * 4);
            f32x4 cN0 = *(const f32x4*)(bs + 64 + q * 4);
            f32x4 cN1 = *(const f32x4*)(bs + 80 + q * 4);
            f32x4 vcn0 = *(const f32x4*)(s.cn_ + l * 32 + 0  + q * 4);
            f32x4 vcn1 = *(const f32x4*)(s.cn_ + l * 32 + 16 + q * 4);

            cR0 = mfma16(a0, bLo, cR0); cR0 = mfma16(a0, bHi, cR0);
            cR1 = mfma16(a1, bLo, cR1); cR1 = mfma16(a1, bHi, cR1);
            cZ0 = mfma16(a2, bLo, cZ0); cZ0 = mfma16(a2, bHi, cZ0);
            cZ1 = mfma16(a3, bLo, cZ1); cZ1 = mfma16(a3, bHi, cZ1);
            cN0 = mfma16(a4, bLo, cN0); cN0 = mfma16(a4, bHi, cN0);
            cN1 = mfma16(a5, bLo, cN1); cN1 = mfma16(a5, bHi, cN1);

            // ---- activations: lane holds hid = q*4+i (+16), batch = n0 ----
            float h0[4], h1[4];
            #pragma unroll
            for (int i = 0; i < 4; ++i) {
                h0[i] = gru_act(cR0[i], cZ0[i], cN0[i], vcn0[i]);
                h1[i] = gru_act(cR1[i], cZ1[i], cN1[i], vcn1[i]);
            }

            // ---- packed b64 writes into [batch][hid] buffer (conflict-free) ----
            u16x4 w0h, w1h, w0l, w1l;
            #pragma unroll
            for (int i = 0; i < 4; ++i) {
                unsigned short t0 = bf_rne(h0[i]);
                unsigned short t1 = bf_rne(h1[i]);
                w0h[i] = t0; w1h[i] = t1;
                w0l[i] = bf_trunc(h0[i] - bf_to_f(t0));
                w1l[i] = bf_trunc(h1[i] - bf_to_f(t1));
            }
            *(u16x4*)(hb  + n0 * HB_ST + 0  + q * 4) = w0h;
            *(u16x4*)(hb  + n0 * HB_ST + 16 + q * 4) = w1h;
            *(u16x4*)(hb2 + n0 * HB_ST + 0  + q * 4) = w0l;
            *(u16x4*)(hb2 + n0 * HB_ST + 16 + q * 4) = w1l;

            // wave-private buffer: drain writes, then read back as B-frag
            asm volatile("s_waitcnt lgkmcnt(0)" ::: "memory");
            bHi = *(const bf16x8*)(hb  + n0 * HB_ST + q * 8);
            bLo = *(const bf16x8*)(hb2 + n0 * HB_ST + q * 8);
            asm volatile("" ::: "memory");
        }

        // ---- FC: out^T = fc_w @ h5^T + fc_b ----
        bf16x8 f0 = *(const bf16x8*)(s.wF + (0  + n0) * 32 + q * 8);
        bf16x8 f1 = *(const bf16x8*)(s.wF + (16 + n0) * 32 + q * 8);
        f32x4 o0 = *(const f32x4*)(s.fb_ + 0  + q * 4);
        f32x4 o1 = *(const f32x4*)(s.fb_ + 16 + q * 4);
        o0 = mfma16(f0, bLo, o0); o0 = mfma16(f0, bHi, o0);
        o1 = mfma16(f1, bLo, o1); o1 = mfma16(f1, bHi, o1);

        // lane holds out[batch = rowBase+n0][emb = t*16 + q*4 + i] -> float4 x2
        float* op = out + (size_t)(rowBase + n0) * 32;
        *(float4*)(op + 0  + q * 4) = *(float4*)&o0;
        *(float4*)(op + 16 + q * 4) = *(float4*)&o1;
    }
}

extern "C" void kernel_launch(void* const* d_in, const int* in_sizes, int n_in,
                              void* d_out, int out_size, void* d_ws, size_t ws_size,
                              hipStream_t stream) {
    (void)n_in; (void)d_ws; (void)ws_size; (void)out_size;
    const float* x    = (const float*)d_in[0];
    const float* w_ih = (const float*)d_in[1];
    // d_in[2] = w_hh: unused (h0 == 0, T == 1)
    const float* b_ih = (const float*)d_in[3];
    const float* b_hh = (const float*)d_in[4];
    const float* fc_w = (const float*)d_in[5];
    const float* fc_b = (const float*)d_in[6];
    float* out = (float*)d_out;

    const int batch  = in_sizes[0] / 32;   // 1048576
    const int nTiles = batch / 16;         // 65536

    // 512 blocks x 512 thr: 2 blocks/CU (LDS 55.9 KB), 4096 waves, 16 tiles/wave.
    gru_fused<<<512, 512, 0, stream>>>(x, w_ih, b_ih, b_hh, fc_w, fc_b, out, nTiles);
}